// Round 1
// baseline (352.097 us; speedup 1.0000x reference)
//
#include <hip/hip_runtime.h>

typedef unsigned short ushort_t;
typedef __attribute__((ext_vector_type(8))) short bf16x8;   // 8 bf16 (4 VGPRs) MFMA A/B frag
typedef __attribute__((ext_vector_type(4))) float f32x4;    // MFMA C/D frag
typedef __attribute__((ext_vector_type(4))) unsigned short u16x4;

__device__ __forceinline__ ushort_t f2bf(float f) {
  unsigned int u = __float_as_uint(f);
  u += 0x7FFFu + ((u >> 16) & 1u);   // RNE (inputs finite)
  return (ushort_t)(u >> 16);
}

__device__ __forceinline__ void gload16(const void* g, void* l) {
  __builtin_amdgcn_global_load_lds((__attribute__((address_space(1))) void*)g,
                                   (__attribute__((address_space(3))) void*)l, 16, 0, 0);
}

// ---------------- prep kernels ----------------

__global__ __launch_bounds__(256) void cast_kernel(const float* __restrict__ in,
                                                   ushort_t* __restrict__ out, int n4) {
  int i = blockIdx.x * 256 + threadIdx.x;
  if (i >= n4) return;
  float4 v = ((const float4*)in)[i];
  u16x4 o = {f2bf(v.x), f2bf(v.y), f2bf(v.z), f2bf(v.w)};
  *(u16x4*)(out + (size_t)i * 4) = o;
}

// fp32 [R][C] -> bf16 [C][R]
__global__ __launch_bounds__(256) void transpose_cast(const float* __restrict__ in,
                                                      ushort_t* __restrict__ out, int R, int C) {
  __shared__ float tile[64][65];
  int c0 = blockIdx.x * 64, r0 = blockIdx.y * 64;
  int tid = threadIdx.x;
  int lr = tid >> 2, q = tid & 3;
  const float* ip = in + (size_t)(r0 + lr) * C + c0 + q * 16;
#pragma unroll
  for (int j = 0; j < 16; ++j) tile[lr][q * 16 + j] = ip[j];
  __syncthreads();
  int oc = tid >> 2;
  ushort_t* op = out + (size_t)(c0 + oc) * R + r0 + q * 16;
#pragma unroll
  for (int j = 0; j < 16; ++j) op[j] = f2bf(tile[q * 16 + j][oc]);
}

// bf16 Vh [bh][2048][64] -> Vt [bh][64][2048]
__global__ __launch_bounds__(256) void transpose_v(const ushort_t* __restrict__ Vh,
                                                   ushort_t* __restrict__ Vt) {
  __shared__ ushort_t tile[64][72];
  int t0 = blockIdx.x * 64, bh = blockIdx.y;
  int tid = threadIdx.x;
  int lr = tid >> 2, q = tid & 3;
  const ushort_t* ip = Vh + ((size_t)bh * 2048 + t0 + lr) * 64 + q * 16;
#pragma unroll
  for (int j = 0; j < 16; ++j) tile[lr][q * 16 + j] = ip[j];
  __syncthreads();
  int d = tid >> 2;
  ushort_t* op = Vt + ((size_t)bh * 64 + d) * 2048 + t0 + q * 16;
#pragma unroll
  for (int j = 0; j < 16; ++j) op[j] = tile[q * 16 + j][d];
}

// ---------------- GEMM: C[M][N] = A[M][K] * Bt[N][K]^T + bias ----------------
// 128x128 tile, BK=32, 4 waves (2x2 of 64x64), m97-style global_load_lds staging.
// MODE 0: write bf16 split Q/K/V [bh][t][d].  MODE 1: write fp32 d_out.

template <int MODE>
__global__ __launch_bounds__(256) void gemm_kernel(
    const ushort_t* __restrict__ A, const ushort_t* __restrict__ Bt,
    const float* __restrict__ bias, float* __restrict__ OutF,
    ushort_t* __restrict__ Qh, ushort_t* __restrict__ Kh, ushort_t* __restrict__ Vh,
    int M, int N, int K) {
  __shared__ __align__(16) char smem[16384];  // A: [0,8192), Bt: [8192,16384)
  const int tid = threadIdx.x;
  const int l = tid & 63;
  const int w = tid >> 6;
  const int m0 = blockIdx.y * 128;
  const int n0 = blockIdx.x * 128;
  const int wr = (w >> 1) * 64;
  const int wc = (w & 1) * 64;

  const f32x4 z = {0.f, 0.f, 0.f, 0.f};
  f32x4 acc[4][4];
#pragma unroll
  for (int i = 0; i < 4; ++i)
#pragma unroll
    for (int j = 0; j < 4; ++j) acc[i][j] = z;

  const int ldsbase = (tid & ~63) * 16;
  for (int kt = 0; kt < K; kt += 32) {
    __syncthreads();
#pragma unroll
    for (int p = 0; p < 2; ++p) {
      int c = p * 256 + tid;
      int row = c >> 2;                         // 64B rows, 4 chunks of 16B
      int gg = (c & 3) ^ ((row >> 1) & 3);      // chunk swizzle (bank-conflict-free frag reads)
      gload16(A + (size_t)(m0 + row) * K + kt + gg * 8, smem + p * 4096 + ldsbase);
      gload16(Bt + (size_t)(n0 + row) * K + kt + gg * 8, smem + 8192 + p * 4096 + ldsbase);
    }
    __syncthreads();
    bf16x8 af[4], bfr[4];
#pragma unroll
    for (int i = 0; i < 4; ++i) {
      int ra = wr + i * 16 + (l & 15);
      af[i] = *(const bf16x8*)(smem + ra * 64 + (((l >> 4) ^ ((ra >> 1) & 3)) << 4));
      int rb = wc + i * 16 + (l & 15);
      bfr[i] = *(const bf16x8*)(smem + 8192 + rb * 64 + (((l >> 4) ^ ((rb >> 1) & 3)) << 4));
    }
#pragma unroll
    for (int mi = 0; mi < 4; ++mi)
#pragma unroll
      for (int ni = 0; ni < 4; ++ni)
        acc[mi][ni] = __builtin_amdgcn_mfma_f32_16x16x32_bf16(af[mi], bfr[ni], acc[mi][ni], 0, 0, 0);
  }

  if (MODE == 0) {
    const int which = n0 >> 10;  // block's 128 cols lie in one of q/k/v
    ushort_t* outp = which == 0 ? Qh : (which == 1 ? Kh : Vh);
#pragma unroll
    for (int ni = 0; ni < 4; ++ni) {
      int col = n0 + wc + ni * 16 + (l & 15);
      float bv = bias[col];
      int cc = col & 1023;
      int h = cc >> 6, d = cc & 63;
#pragma unroll
      for (int mi = 0; mi < 4; ++mi) {
#pragma unroll
        for (int r = 0; r < 4; ++r) {
          int grow = m0 + wr + mi * 16 + (l >> 4) * 4 + r;
          int bb = grow >> 11, t = grow & 2047;
          outp[((size_t)(bb * 16 + h) * 2048 + t) * 64 + d] = f2bf(acc[mi][ni][r] + bv);
        }
      }
    }
  } else {
#pragma unroll
    for (int ni = 0; ni < 4; ++ni) {
      int col = n0 + wc + ni * 16 + (l & 15);
      float bv = bias[col];
#pragma unroll
      for (int mi = 0; mi < 4; ++mi) {
#pragma unroll
        for (int r = 0; r < 4; ++r) {
          int grow = m0 + wr + mi * 16 + (l >> 4) * 4 + r;
          OutF[(size_t)grow * 1024 + col] = acc[mi][ni][r] + bv;
        }
      }
    }
  }
}

// ---------------- flash attention ----------------
// grid (qt=32, bh=64), 256 thr. QBLK=64 (wave w owns rows q0+16w..+16), KVBLK=64.
// K_lds [64 kpos][64 d] swizzled; V_lds = Vt tile [64 d][64 kpos] swizzled;
// P_lds per-wave [16][64] bf16 swizzled.

__global__ __launch_bounds__(256) void attn_kernel(
    const ushort_t* __restrict__ Qh, const ushort_t* __restrict__ Kh,
    const ushort_t* __restrict__ Vt, ushort_t* __restrict__ Y) {
  __shared__ __align__(16) char smem[24576];  // K:0..8K, V:8K..16K, P:16K..24K
  const int qt = blockIdx.x;
  const int bh = blockIdx.y;
  const int tid = threadIdx.x;
  const int l = tid & 63;
  const int w = tid >> 6;
  const int q0 = qt * 64;
  const int qw = q0 + w * 16;
  const size_t baseK = (size_t)bh * 2048 * 64;

  bf16x8 qf[2];
  {
    const ushort_t* qp = Qh + baseK + (size_t)(qw + (l & 15)) * 64 + ((l >> 4) * 8);
    qf[0] = *(const bf16x8*)qp;
    qf[1] = *(const bf16x8*)(qp + 32);
  }
  const f32x4 z = {0.f, 0.f, 0.f, 0.f};
  f32x4 o[4] = {z, z, z, z};
  float mrun[4] = {-3e38f, -3e38f, -3e38f, -3e38f};
  float lrun[4] = {0.f, 0.f, 0.f, 0.f};
  const int ldsbase = (tid & ~63) * 16;

  for (int kt2 = 0; kt2 <= qt; ++kt2) {
    const int kv0 = kt2 * 64;
    __syncthreads();
#pragma unroll
    for (int p = 0; p < 2; ++p) {
      int c = p * 256 + tid;
      int row = c >> 3;                    // 128B rows, 8 chunks
      int gg = (c & 7) ^ (row & 7);        // swizzle
      gload16(Kh + baseK + (size_t)(kv0 + row) * 64 + gg * 8, smem + p * 4096 + ldsbase);
      gload16(Vt + (size_t)bh * 64 * 2048 + (size_t)row * 2048 + kv0 + gg * 8,
              smem + 8192 + p * 4096 + ldsbase);
    }
    __syncthreads();

    // S = Q K^T
    f32x4 s[4] = {z, z, z, z};
#pragma unroll
    for (int kc = 0; kc < 2; ++kc) {
#pragma unroll
      for (int ng = 0; ng < 4; ++ng) {
        int rk = ng * 16 + (l & 15);
        bf16x8 kf = *(const bf16x8*)(smem + rk * 128 + (((kc * 4 + (l >> 4)) ^ (rk & 7)) << 4));
        s[ng] = __builtin_amdgcn_mfma_f32_16x16x32_bf16(qf[kc], kf, s[ng], 0, 0, 0);
      }
    }

    // scale + causal mask + row max (rows live at (l>>4)*4+r, cols at ng*16+(l&15))
    float rm[4] = {-3e38f, -3e38f, -3e38f, -3e38f};
    const bool diag = (kt2 == qt);
#pragma unroll
    for (int ng = 0; ng < 4; ++ng) {
      int colk = ng * 16 + (l & 15);
#pragma unroll
      for (int r = 0; r < 4; ++r) {
        float sv = s[ng][r] * 0.125f;
        if (diag && (colk > w * 16 + (l >> 4) * 4 + r)) sv = -3e38f;
        s[ng][r] = sv;
        rm[r] = fmaxf(rm[r], sv);
      }
    }
#pragma unroll
    for (int off = 1; off <= 8; off <<= 1)
#pragma unroll
      for (int r = 0; r < 4; ++r) rm[r] = fmaxf(rm[r], __shfl_xor(rm[r], off));

    float alpha[4], rs[4];
#pragma unroll
    for (int r = 0; r < 4; ++r) {
      float mn = fmaxf(mrun[r], rm[r]);
      alpha[r] = __expf(mrun[r] - mn);
      mrun[r] = mn;
      rs[r] = 0.f;
    }
#pragma unroll
    for (int ng = 0; ng < 4; ++ng)
#pragma unroll
      for (int r = 0; r < 4; ++r) {
        float pv = __expf(s[ng][r] - mrun[r]);
        s[ng][r] = pv;
        rs[r] += pv;
      }
#pragma unroll
    for (int off = 1; off <= 8; off <<= 1)
#pragma unroll
      for (int r = 0; r < 4; ++r) rs[r] += __shfl_xor(rs[r], off);
#pragma unroll
    for (int r = 0; r < 4; ++r) lrun[r] = lrun[r] * alpha[r] + rs[r];
#pragma unroll
    for (int dg = 0; dg < 4; ++dg)
#pragma unroll
      for (int r = 0; r < 4; ++r) o[dg][r] *= alpha[r];

    // P -> LDS (bf16, swizzled), per-wave buffer
#pragma unroll
    for (int ng = 0; ng < 4; ++ng) {
      int colp = ng * 16 + (l & 15);
#pragma unroll
      for (int r = 0; r < 4; ++r) {
        int rowp = (l >> 4) * 4 + r;
        int byte = 16384 + w * 2048 + rowp * 128 + (((colp >> 3) ^ (rowp & 7)) << 4) + (colp & 7) * 2;
        *(ushort_t*)(smem + byte) = f2bf(s[ng][r]);
      }
    }

    // O += P V
#pragma unroll
    for (int kc = 0; kc < 2; ++kc) {
      int rp = l & 15;
      bf16x8 pf = *(const bf16x8*)(smem + 16384 + w * 2048 + rp * 128 +
                                   (((kc * 4 + (l >> 4)) ^ (rp & 7)) << 4));
#pragma unroll
      for (int dg = 0; dg < 4; ++dg) {
        int rv = dg * 16 + (l & 15);
        bf16x8 vf = *(const bf16x8*)(smem + 8192 + rv * 128 +
                                     (((kc * 4 + (l >> 4)) ^ (rv & 7)) << 4));
        o[dg] = __builtin_amdgcn_mfma_f32_16x16x32_bf16(pf, vf, o[dg], 0, 0, 0);
      }
    }
  }

  const int b = bh >> 4, h = bh & 15;
#pragma unroll
  for (int dg = 0; dg < 4; ++dg)
#pragma unroll
    for (int r = 0; r < 4; ++r) {
      int q = qw + (l >> 4) * 4 + r;
      int col = h * 64 + dg * 16 + (l & 15);
      Y[((size_t)(b * 2048 + q)) * 1024 + col] = f2bf(o[dg][r] / lrun[r]);
    }
}

// ---------------- launch ----------------

extern "C" void kernel_launch(void* const* d_in, const int* in_sizes, int n_in,
                              void* d_out, int out_size, void* d_ws, size_t ws_size,
                              hipStream_t stream) {
  const float* x      = (const float*)d_in[0];
  const float* w_qkv  = (const float*)d_in[1];
  const float* b_qkv  = (const float*)d_in[2];
  const float* w_proj = (const float*)d_in[3];
  const float* b_proj = (const float*)d_in[4];
  float* out = (float*)d_out;

  char* ws = (char*)d_ws;
  // layout (bytes)
  ushort_t* xb = (ushort_t*)(ws + 0);            // 16 MB  x bf16 [8192][1024]; reused as y after attn
  ushort_t* Wq = (ushort_t*)(ws + (16u << 20));  //  6 MB  w_qkv^T bf16 [3072][1024]
  ushort_t* Wp = (ushort_t*)(ws + (22u << 20));  //  2 MB  w_proj^T bf16 [1024][1024]
  ushort_t* Qh = (ushort_t*)(ws + (24u << 20));  // 16 MB  [64][2048][64]
  ushort_t* Kh = (ushort_t*)(ws + (40u << 20));  // 16 MB
  ushort_t* Vh = (ushort_t*)(ws + (56u << 20));  // 16 MB
  ushort_t* Vt = (ushort_t*)(ws + (72u << 20));  // 16 MB  [64][64][2048]

  cast_kernel<<<8192, 256, 0, stream>>>(x, xb, 2097152);
  transpose_cast<<<dim3(48, 16), 256, 0, stream>>>(w_qkv, Wq, 1024, 3072);
  transpose_cast<<<dim3(16, 16), 256, 0, stream>>>(w_proj, Wp, 1024, 1024);

  gemm_kernel<0><<<dim3(24, 64), 256, 0, stream>>>(xb, Wq, b_qkv, nullptr, Qh, Kh, Vh,
                                                   8192, 3072, 1024);
  transpose_v<<<dim3(32, 64), 256, 0, stream>>>(Vh, Vt);
  attn_kernel<<<dim3(32, 64), 256, 0, stream>>>(Qh, Kh, Vt, xb /* y overwrites x_bf16 */);
  gemm_kernel<1><<<dim3(8, 64), 256, 0, stream>>>(xb, Wp, b_proj, out, nullptr, nullptr, nullptr,
                                                  8192, 1024, 1024);
}